// Round 1
// baseline (179.295 us; speedup 1.0000x reference)
//
#include <hip/hip_runtime.h>
#include <hip/hip_bf16.h>

// LIF neuron forward scan.
// x_seq: (T=64, B=32, F=8192) fp32. Outputs: spike_seq then mem_seq, same shape,
// concatenated flat in d_out.
//
// Recurrence per (b,f):
//   mem = mem * 0.5 + x          (tau_mem=2 -> 1-decay = 0.5; dt=1)
//   spike = (mem >= 1.0) ? 1 : 0
//   mem = spike ? 0 : mem        (v_reset = 0, detach_reset irrelevant in fwd)
//
// Memory-bound: 192 MiB total traffic -> ~30 us floor at 6.3 TB/s.

#define T_STEPS 64
#define BF (32 * 8192)          // 262144 elements per timestep
#define BF4 (BF / 4)            // 65536 float4 groups

__global__ __launch_bounds__(256) void lif_fwd_kernel(
    const float4* __restrict__ x,        // T * BF4
    float4* __restrict__ spike_out,      // T * BF4
    float4* __restrict__ mem_out)        // T * BF4
{
    const int idx = blockIdx.x * blockDim.x + threadIdx.x;  // 0 .. BF4-1

    float4 mem = make_float4(0.f, 0.f, 0.f, 0.f);

#pragma unroll 8
    for (int t = 0; t < T_STEPS; ++t) {
        const float4 xv = x[t * BF4 + idx];

        mem.x = mem.x * 0.5f + xv.x;
        mem.y = mem.y * 0.5f + xv.y;
        mem.z = mem.z * 0.5f + xv.z;
        mem.w = mem.w * 0.5f + xv.w;

        float4 sp;
        sp.x = (mem.x >= 1.0f) ? 1.0f : 0.0f;
        sp.y = (mem.y >= 1.0f) ? 1.0f : 0.0f;
        sp.z = (mem.z >= 1.0f) ? 1.0f : 0.0f;
        sp.w = (mem.w >= 1.0f) ? 1.0f : 0.0f;

        mem.x = (sp.x != 0.0f) ? 0.0f : mem.x;
        mem.y = (sp.y != 0.0f) ? 0.0f : mem.y;
        mem.z = (sp.z != 0.0f) ? 0.0f : mem.z;
        mem.w = (sp.w != 0.0f) ? 0.0f : mem.w;

        spike_out[t * BF4 + idx] = sp;
        mem_out[t * BF4 + idx]   = mem;
    }
}

extern "C" void kernel_launch(void* const* d_in, const int* in_sizes, int n_in,
                              void* d_out, int out_size, void* d_ws, size_t ws_size,
                              hipStream_t stream) {
    const float4* x = (const float4*)d_in[0];
    float4* spike_out = (float4*)d_out;                       // first T*BF floats
    float4* mem_out   = (float4*)d_out + (size_t)T_STEPS * BF4;  // second half

    lif_fwd_kernel<<<BF4 / 256, 256, 0, stream>>>(x, spike_out, mem_out);
}

// Round 2
// 176.966 us; speedup vs baseline: 1.0132x; 1.0132x over previous
//
#include <hip/hip_runtime.h>
#include <hip/hip_bf16.h>

// LIF neuron forward scan.
// x_seq: (T=64, B=32, F=8192) fp32. Outputs: spike_seq then mem_seq, same shape,
// concatenated flat in d_out.
//
// Recurrence per (b,f):
//   mem = mem * 0.5 + x          (tau_mem=2 -> 1-decay = 0.5; dt=1)
//   spike = (mem >= 1.0) ? 1 : 0
//   mem = spike ? 0 : mem        (v_reset = 0)
//
// Memory-bound: 201 MiB total traffic -> ~32 us floor at 6.3 TB/s.
// R2: float2/thread -> 131072 threads = 8 waves/CU (2/SIMD) instead of 1/SIMD,
// nontemporal loads/stores (pure streaming, no reuse).

#define T_STEPS 64
#define BF (32 * 8192)          // 262144 elements per timestep
#define BF2 (BF / 2)            // 131072 float2 groups

typedef float v2f __attribute__((ext_vector_type(2)));

__global__ __launch_bounds__(256) void lif_fwd_kernel(
    const v2f* __restrict__ x,        // T * BF2
    v2f* __restrict__ spike_out,      // T * BF2
    v2f* __restrict__ mem_out)        // T * BF2
{
    const int idx = blockIdx.x * blockDim.x + threadIdx.x;  // 0 .. BF2-1

    v2f mem = {0.f, 0.f};

#pragma unroll 8
    for (int t = 0; t < T_STEPS; ++t) {
        const v2f xv = __builtin_nontemporal_load(&x[t * BF2 + idx]);

        mem.x = mem.x * 0.5f + xv.x;
        mem.y = mem.y * 0.5f + xv.y;

        v2f sp;
        sp.x = (mem.x >= 1.0f) ? 1.0f : 0.0f;
        sp.y = (mem.y >= 1.0f) ? 1.0f : 0.0f;

        mem.x = (sp.x != 0.0f) ? 0.0f : mem.x;
        mem.y = (sp.y != 0.0f) ? 0.0f : mem.y;

        __builtin_nontemporal_store(sp, &spike_out[t * BF2 + idx]);
        __builtin_nontemporal_store(mem, &mem_out[t * BF2 + idx]);
    }
}

extern "C" void kernel_launch(void* const* d_in, const int* in_sizes, int n_in,
                              void* d_out, int out_size, void* d_ws, size_t ws_size,
                              hipStream_t stream) {
    const v2f* x = (const v2f*)d_in[0];
    v2f* spike_out = (v2f*)d_out;                              // first T*BF floats
    v2f* mem_out   = (v2f*)d_out + (size_t)T_STEPS * BF2;      // second half

    lif_fwd_kernel<<<BF2 / 256, 256, 0, stream>>>(x, spike_out, mem_out);
}